// Round 1
// baseline (334.694 us; speedup 1.0000x reference)
//
#include <hip/hip_runtime.h>
#include <math.h>

#define D 256
#define H2 512
#define HEADS 8
#define DH 32
#define PATCHSZ 5
#define L 25
#define GH 64
#define GW 64
#define NN 4096
#define EPS 1e-5f
#define SCALE 0.17677669529663687f  // 1/sqrt(32)

__device__ __forceinline__ bool act_at(const int* __restrict__ active, int h, int w) {
    if (h < 0 || h >= GH || w < 0 || w >= GW) return false;
    if (h == 2 && w == 2) return false;   // ap.at[:, center, center].set(False) quirk
    return active[h * GW + w] != 0;
}

// ---------------- Kernel A: per-node projections ----------------
// Q1,K1,V1 = (x * act') @ {Wq1,Wk1,Wv1} + b ;  K2,V2 = memory @ {Wk2,Wv2} + b
__global__ __launch_bounds__(256)
void proj_kernel(const float* __restrict__ x,
                 const float* __restrict__ mem,
                 const int* __restrict__ active,
                 const float* __restrict__ attn_w,
                 const float* __restrict__ attn_b,
                 const float* __restrict__ pattn_w,
                 const float* __restrict__ pattn_b,
                 float* __restrict__ Q1, float* __restrict__ K1, float* __restrict__ V1,
                 float* __restrict__ K2, float* __restrict__ V2) {
    const int n = blockIdx.x;
    const int h = n / GW, w = n % GW;
    const int j = threadIdx.x;
    __shared__ float ys[D];
    __shared__ float ms[D];
    bool a = act_at(active, h, w);
    ys[j] = a ? x[n * D + j] : 0.0f;
    ms[j] = mem[n * D + j];
    __syncthreads();
    const float* Wq  = attn_w;
    const float* Wk  = attn_w + D * D;
    const float* Wv  = attn_w + 2 * D * D;
    const float* Wk2 = pattn_w + D * D;
    const float* Wv2 = pattn_w + 2 * D * D;
    float aq = attn_b[j], ak = attn_b[D + j], av = attn_b[2 * D + j];
    float bk2 = pattn_b[D + j], bv2 = pattn_b[2 * D + j];
    for (int i = 0; i < D; ++i) {
        float yv = ys[i], mv = ms[i];
        aq  = fmaf(yv, Wq[i * D + j], aq);
        ak  = fmaf(yv, Wk[i * D + j], ak);
        av  = fmaf(yv, Wv[i * D + j], av);
        bk2 = fmaf(mv, Wk2[i * D + j], bk2);
        bv2 = fmaf(mv, Wv2[i * D + j], bv2);
    }
    Q1[n * D + j] = aq;
    K1[n * D + j] = ak;
    V1[n * D + j] = av;
    K2[n * D + j] = bk2;
    V2[n * D + j] = bv2;
}

// Layernorm over 256 elems held one-per-thread; returns normalized value.
__device__ __forceinline__ float ln_norm(float res, const float* __restrict__ g,
                                         const float* __restrict__ b,
                                         float* red, int j) {
    float v = res, v2 = res * res;
    #pragma unroll
    for (int off = 32; off > 0; off >>= 1) {
        v  += __shfl_down(v, off);
        v2 += __shfl_down(v2, off);
    }
    int wid = j >> 6;
    if ((j & 63) == 0) { red[wid] = v; red[4 + wid] = v2; }
    __syncthreads();
    if (j == 0) {
        float s1 = red[0] + red[1] + red[2] + red[3];
        float s2 = red[4] + red[5] + red[6] + red[7];
        float mu = s1 * (1.0f / D);
        float var = s2 * (1.0f / D) - mu * mu;
        red[8] = mu;
        red[9] = rsqrtf(var + EPS);
    }
    __syncthreads();
    float r = (res - red[8]) * red[9] * g[j] + b[j];
    __syncthreads();   // protect red[] for next call
    return r;
}

// ---------------- Kernel B: per-node attention + FF ----------------
__global__ __launch_bounds__(256)
void attn_kernel(const float* __restrict__ x,
                 const int* __restrict__ active,
                 const float* __restrict__ attn_w,  const float* __restrict__ attn_b,
                 const float* __restrict__ pattn_w, const float* __restrict__ pattn_b,
                 const float* __restrict__ ff_w1,   const float* __restrict__ ff_b1,
                 const float* __restrict__ ff_w2,   const float* __restrict__ ff_b2,
                 const float* __restrict__ ln_g,    const float* __restrict__ ln_b,
                 const float* __restrict__ Q1, const float* __restrict__ K1,
                 const float* __restrict__ V1, const float* __restrict__ K2,
                 const float* __restrict__ V2,
                 float* __restrict__ out) {
    const int n = blockIdx.x;
    const int h = n / GW, w = n % GW;
    const int j = threadIdx.x;

    __shared__ float sm_s[D];          // current state vector
    __shared__ float sm_t[D];          // Q-proj / attention-output scratch
    __shared__ float sm_h[H2];         // FF hidden
    __shared__ float sm_sc[HEADS * L]; // scores
    __shared__ float sm_aw[HEADS * L]; // attention weights
    __shared__ float sm_red[12];
    __shared__ int   sm_nb[L];
    __shared__ int   sm_v1[L];

    bool a_c = act_at(active, h, w);
    if (!a_c) {
        out[n * D + j] = 0.0f;
        if (j == 0) out[(size_t)NN * D + n] = 0.0f;
        return;
    }
    if (j == 0) out[(size_t)NN * D + n] = 1.0f;

    if (j < L) {
        int pi = j / PATCHSZ, pj = j % PATCHSZ;
        int hh = h + pi - 2, ww = w + pj - 2;
        bool ib = (hh >= 0 && hh < GH && ww >= 0 && ww < GW);
        sm_nb[j] = ib ? hh * GW + ww : -1;
        sm_v1[j] = act_at(active, hh, ww) ? 1 : 0;
    }
    float q_r = x[n * D + j];          // act' true -> masked x == x
    sm_t[j] = Q1[n * D + j];
    __syncthreads();

    // ---- MHA1 scores (masked) ----
    if (j < HEADS * L) {
        int head = j / L, l = j - head * L;
        if (sm_v1[l]) {
            const float* kr = K1 + (size_t)sm_nb[l] * D + head * DH;
            const float* qr = sm_t + head * DH;
            float s = 0.0f;
            #pragma unroll
            for (int d = 0; d < DH; ++d) s = fmaf(qr[d], kr[d], s);
            sm_sc[j] = s * SCALE;
        }
    }
    __syncthreads();
    if (j < HEADS) {
        float m = -1e30f;
        for (int l = 0; l < L; ++l) if (sm_v1[l]) m = fmaxf(m, sm_sc[j * L + l]);
        float e[L], sum = 0.0f;
        for (int l = 0; l < L; ++l) {
            float v = sm_v1[l] ? expf(sm_sc[j * L + l] - m) : 0.0f;
            e[l] = v; sum += v;
        }
        float inv = 1.0f / sum;
        for (int l = 0; l < L; ++l) sm_aw[j * L + l] = e[l] * inv;
    }
    __syncthreads();
    // ---- MHA1 PV ----
    {
        int head = j >> 5;
        float o = 0.0f;
        for (int l = 0; l < L; ++l) {
            if (sm_v1[l]) o = fmaf(sm_aw[head * L + l], V1[(size_t)sm_nb[l] * D + j], o);
        }
        __syncthreads();           // done reading sm_t (Q1)
        sm_t[j] = o;
    }
    __syncthreads();
    // ---- out-proj + residual + LN0 ----
    const float* Wo1 = attn_w + 3 * D * D;
    float acc = attn_b[3 * D + j];
    for (int i = 0; i < D; ++i) acc = fmaf(sm_t[i], Wo1[i * D + j], acc);
    float res = q_r + acc;
    float sv = ln_norm(res, ln_g, ln_b, sm_red, j);          // ln row 0
    sm_s[j] = sv;
    __syncthreads();

    // ---- MHA2: Q2 = s @ Wq2 + b ----
    const float* Wq2 = pattn_w;
    acc = pattn_b[j];
    for (int i = 0; i < D; ++i) acc = fmaf(sm_s[i], Wq2[i * D + j], acc);
    sm_t[j] = acc;
    __syncthreads();
    // scores (no mask; OOB -> bias-only K)
    if (j < HEADS * L) {
        int head = j / L, l = j - head * L;
        const float* kr = (sm_nb[l] >= 0) ? (K2 + (size_t)sm_nb[l] * D + head * DH)
                                          : (pattn_b + D + head * DH);
        const float* qr = sm_t + head * DH;
        float s = 0.0f;
        #pragma unroll
        for (int d = 0; d < DH; ++d) s = fmaf(qr[d], kr[d], s);
        sm_sc[j] = s * SCALE;
    }
    __syncthreads();
    if (j < HEADS) {
        float m = -1e30f;
        for (int l = 0; l < L; ++l) m = fmaxf(m, sm_sc[j * L + l]);
        float e[L], sum = 0.0f;
        for (int l = 0; l < L; ++l) { e[l] = expf(sm_sc[j * L + l] - m); sum += e[l]; }
        float inv = 1.0f / sum;
        for (int l = 0; l < L; ++l) sm_aw[j * L + l] = e[l] * inv;
    }
    __syncthreads();
    {
        int head = j >> 5;
        float o = 0.0f;
        for (int l = 0; l < L; ++l) {
            float v = (sm_nb[l] >= 0) ? V2[(size_t)sm_nb[l] * D + j] : pattn_b[2 * D + j];
            o = fmaf(sm_aw[head * L + l], v, o);
        }
        __syncthreads();
        sm_t[j] = o;
    }
    __syncthreads();
    const float* Wo2 = pattn_w + 3 * D * D;
    acc = pattn_b[3 * D + j];
    for (int i = 0; i < D; ++i) acc = fmaf(sm_t[i], Wo2[i * D + j], acc);
    res = sm_s[j] + acc;
    sv = ln_norm(res, ln_g + 2 * D, ln_b + 2 * D, sm_red, j); // ln row 2
    sm_s[j] = sv;
    __syncthreads();

    // ---- FF ----
    for (int k = j; k < H2; k += D) {
        float a2 = ff_b1[k];
        for (int i = 0; i < D; ++i) a2 = fmaf(sm_s[i], ff_w1[i * H2 + k], a2);
        sm_h[k] = fmaxf(a2, 0.0f);
    }
    __syncthreads();
    acc = ff_b2[j];
    for (int k = 0; k < H2; ++k) acc = fmaf(sm_h[k], ff_w2[k * D + j], acc);
    res = sm_s[j] + acc;
    sv = ln_norm(res, ln_g + D, ln_b + D, sm_red, j);         // ln row 1
    out[n * D + j] = sv;
}

extern "C" void kernel_launch(void* const* d_in, const int* in_sizes, int n_in,
                              void* d_out, int out_size, void* d_ws, size_t ws_size,
                              hipStream_t stream) {
    const float* x       = (const float*)d_in[0];
    const float* memory  = (const float*)d_in[1];
    const int*   active  = (const int*)d_in[2];
    const float* attn_w  = (const float*)d_in[3];
    const float* attn_b  = (const float*)d_in[4];
    const float* pattn_w = (const float*)d_in[5];
    const float* pattn_b = (const float*)d_in[6];
    const float* ff_w1   = (const float*)d_in[7];
    const float* ff_b1   = (const float*)d_in[8];
    const float* ff_w2   = (const float*)d_in[9];
    const float* ff_b2   = (const float*)d_in[10];
    const float* ln_g    = (const float*)d_in[11];
    const float* ln_b    = (const float*)d_in[12];
    float* out = (float*)d_out;

    float* ws = (float*)d_ws;
    float* Q1 = ws;
    float* K1 = ws + (size_t)NN * D;
    float* V1 = ws + 2 * (size_t)NN * D;
    float* K2 = ws + 3 * (size_t)NN * D;
    float* V2 = ws + 4 * (size_t)NN * D;

    hipLaunchKernelGGL(proj_kernel, dim3(NN), dim3(D), 0, stream,
                       x, memory, active, attn_w, attn_b, pattn_w, pattn_b,
                       Q1, K1, V1, K2, V2);
    hipLaunchKernelGGL(attn_kernel, dim3(NN), dim3(D), 0, stream,
                       x, active, attn_w, attn_b, pattn_w, pattn_b,
                       ff_w1, ff_b1, ff_w2, ff_b2, ln_g, ln_b,
                       Q1, K1, V1, K2, V2, out);
}